// Round 1
// baseline (16290.280 us; speedup 1.0000x reference)
//
#include <hip/hip_runtime.h>
#include <cstdint>

#define NF 128   // node feature / hidden width
#define G4 512   // 4*H gates

typedef float v2f __attribute__((ext_vector_type(2)));

__device__ __forceinline__ float frcp(float x) { return __builtin_amdgcn_rcpf(x); }
__device__ __forceinline__ float fsig(float x) { return frcp(1.f + __expf(-x)); }
__device__ __forceinline__ float ftanh(float x) {
  float e = __expf(2.f * x);
  return 1.f - 2.f * frcp(e + 1.f);
}

// ---------------- small utility kernels ----------------

__global__ void k_fill(float* p, float v, int n) {
  int i = blockIdx.x * blockDim.x + threadIdx.x;
  if (i < n) p[i] = v;
}

// Detect whether edge_index is int64 (all hi-words of first 1024 values zero)
// or int32 (odd slots hold real random indices, ~surely nonzero somewhere).
__global__ void k_detect_i64(const int* e, int npairs, int* flag) {
  int f = 1;
  for (int i = 1; i < 2 * npairs; i += 2)
    if (e[i] != 0) { f = 0; break; }
  *flag = f;
}

__device__ __forceinline__ int eidx(const void* edges, int i64, size_t pos) {
  if (i64) return (int)((const long long*)edges)[pos];
  return ((const int*)edges)[pos];
}

__global__ void k_count(const void* __restrict__ edges, const int* __restrict__ flag,
                        float* __restrict__ deg, int E) {
  int e = blockIdx.x * blockDim.x + threadIdx.x;
  if (e < E) {
    int d = eidx(edges, *flag, (size_t)E + e);
    unsafeAtomicAdd(&deg[d], 1.0f);
  }
}

__global__ void k_rsqrt(float* p, int n) {
  int i = blockIdx.x * blockDim.x + threadIdx.x;
  if (i < n) p[i] = rsqrtf(p[i]);  // deg >= 1 always (self loop)
}

__global__ void k_t128(const float* __restrict__ in, float* __restrict__ out) {
  int n = blockIdx.x, k = threadIdx.x;
  out[n * 128 + k] = in[k * 128 + n];
}

__global__ void k_add(const float* a, const float* b, float* o, int n) {
  int i = blockIdx.x * blockDim.x + threadIdx.x;
  if (i < n) o[i] = a[i] + b[i];
}

// ---------------- GEMM: C[M,N] = A[M,K] @ B[N,K]^T (+bias) ----------------
// BM=BN=64, BK=32, 256 threads, 4x4 acc per thread.
__global__ __launch_bounds__(256)
void gemm_bt(const float* __restrict__ A, const float* __restrict__ B,
             const float* __restrict__ bias, float* __restrict__ C,
             int M, int N, int K) {
  __shared__ float As[32][68];
  __shared__ float Bs[32][68];
  const int bm = blockIdx.x * 64;
  const int bn = blockIdx.y * 64;
  const int tid = threadIdx.x;
  const int tm = (tid & 15) << 2;
  const int tn = (tid >> 4) << 2;
  float acc[4][4] = {};

  for (int k0 = 0; k0 < K; k0 += 32) {
#pragma unroll
    for (int l = 0; l < 2; ++l) {
      int idx = tid + l * 256;      // 0..511
      int row = idx >> 3;           // 0..63
      int k4 = (idx & 7) << 2;      // 0,4,...,28
      int ar = bm + row; ar = ar < M ? ar : M - 1;
      float4 av = *(const float4*)(A + (size_t)ar * K + k0 + k4);
      As[k4 + 0][row] = av.x; As[k4 + 1][row] = av.y;
      As[k4 + 2][row] = av.z; As[k4 + 3][row] = av.w;
      int br = bn + row; br = br < N ? br : N - 1;
      float4 bv = *(const float4*)(B + (size_t)br * K + k0 + k4);
      Bs[k4 + 0][row] = bv.x; Bs[k4 + 1][row] = bv.y;
      Bs[k4 + 2][row] = bv.z; Bs[k4 + 3][row] = bv.w;
    }
    __syncthreads();
#pragma unroll
    for (int kk = 0; kk < 32; ++kk) {
      float4 a = *(const float4*)&As[kk][tm];
      float4 b = *(const float4*)&Bs[kk][tn];
      float av[4] = {a.x, a.y, a.z, a.w};
      float bv[4] = {b.x, b.y, b.z, b.w};
#pragma unroll
      for (int i = 0; i < 4; ++i)
#pragma unroll
        for (int jj = 0; jj < 4; ++jj)
          acc[i][jj] = __builtin_fmaf(av[i], bv[jj], acc[i][jj]);
    }
    __syncthreads();
  }

  float4 bv4;
  if (bias) bv4 = *(const float4*)(bias + bn + tn);
  else bv4 = make_float4(0.f, 0.f, 0.f, 0.f);
#pragma unroll
  for (int i = 0; i < 4; ++i) {
    int row = bm + tm + i;
    if (row < M) {
      float4 v;
      v.x = acc[i][0] + bv4.x;
      v.y = acc[i][1] + bv4.y;
      v.z = acc[i][2] + bv4.z;
      v.w = acc[i][3] + bv4.w;
      *(float4*)(C + (size_t)row * N + bn + tn) = v;
    }
  }
}

// ---------------- GCN edge aggregation (atomic scatter) ----------------
__global__ __launch_bounds__(256)
void k_aggregate(const float* __restrict__ xw, const void* __restrict__ edges,
                 const int* __restrict__ flag, const float* __restrict__ dinv,
                 float* __restrict__ out, int E) {
  int e = blockIdx.x * 8 + (threadIdx.x >> 5);
  if (e >= E) return;
  int i64 = *flag;
  int s = eidx(edges, i64, e);
  int d = eidx(edges, i64, (size_t)E + e);
  float nrm = dinv[s] * dinv[d];
  int f4 = threadIdx.x & 31;
  float4 v = ((const float4*)xw)[(size_t)s * 32 + f4];
  float* op = out + (size_t)d * 128 + f4 * 4;
  unsafeAtomicAdd(op + 0, v.x * nrm);
  unsafeAtomicAdd(op + 1, v.y * nrm);
  unsafeAtomicAdd(op + 2, v.z * nrm);
  unsafeAtomicAdd(op + 3, v.w * nrm);
}

// h = relu(agg + xw*dinv^2 + b), in place on agg
__global__ void k_finish(float* __restrict__ h, const float* __restrict__ xw,
                         const float* __restrict__ dinv, const float* __restrict__ b,
                         int N) {
  int i4 = blockIdx.x * blockDim.x + threadIdx.x;
  if (i4 >= N * 32) return;
  int n = i4 >> 5;
  int f4 = (i4 & 31) << 2;
  float di = dinv[n];
  float s = di * di;
  float4 ag = ((const float4*)h)[i4];
  float4 xv = ((const float4*)xw)[i4];
  float4 bv = *(const float4*)(b + f4);
  float4 r;
  r.x = fmaxf(__builtin_fmaf(xv.x, s, ag.x) + bv.x, 0.f);
  r.y = fmaxf(__builtin_fmaf(xv.y, s, ag.y) + bv.y, 0.f);
  r.z = fmaxf(__builtin_fmaf(xv.z, s, ag.z) + bv.z, 0.f);
  r.w = fmaxf(__builtin_fmaf(xv.w, s, ag.w) + bv.w, 0.f);
  ((float4*)h)[i4] = r;
}

// ---------------- sequential LSTM scan: 1 workgroup, 512 threads ----------------
// thread j owns gate unit j (0..511); W_hh row j kept in VGPRs.
__global__ __launch_bounds__(512)
void k_lstm(const float* __restrict__ g_in, const float* __restrict__ W_hh,
            float* __restrict__ hs, int T) {
  const int j = threadIdx.x;
  __shared__ float4 h4s[32];     // h vector (128 floats)
  __shared__ float gates[512];

  v2f w2[64];
  {
    const float4* wr = (const float4*)(W_hh + (size_t)j * 128);
#pragma unroll
    for (int k = 0; k < 32; ++k) {
      float4 wv = wr[k];
      w2[2 * k + 0] = (v2f){wv.x, wv.y};
      w2[2 * k + 1] = (v2f){wv.z, wv.w};
    }
  }
  if (j < 32) h4s[j] = make_float4(0.f, 0.f, 0.f, 0.f);
  float c = 0.f;
  float gnext = g_in[j];
  __syncthreads();

  for (int t = 0; t < T; ++t) {
    float gcur = gnext;
    int tnext = (t + 1 < T) ? t + 1 : t;
    gnext = g_in[(size_t)tnext * G4 + j];   // prefetch next step

    v2f a0 = {0.f, 0.f}, a1 = {0.f, 0.f}, a2 = {0.f, 0.f}, a3 = {0.f, 0.f};
#pragma unroll
    for (int k = 0; k < 32; k += 2) {
      float4 h0 = h4s[k];
      float4 h1 = h4s[k + 1];
      a0 = __builtin_elementwise_fma(w2[2 * k + 0], (v2f){h0.x, h0.y}, a0);
      a1 = __builtin_elementwise_fma(w2[2 * k + 1], (v2f){h0.z, h0.w}, a1);
      a2 = __builtin_elementwise_fma(w2[2 * k + 2], (v2f){h1.x, h1.y}, a2);
      a3 = __builtin_elementwise_fma(w2[2 * k + 3], (v2f){h1.z, h1.w}, a3);
    }
    v2f s01 = (a0 + a1) + (a2 + a3);
    float x = gcur + s01.x + s01.y;
    float a = (j >= 256 && j < 384) ? ftanh(x) : fsig(x);
    gates[j] = a;
    __syncthreads();
    if (j < 128) {
      float i_ = gates[j];
      float f_ = gates[j + 128];
      float g_ = gates[j + 256];
      float o_ = gates[j + 384];
      c = __builtin_fmaf(f_, c, i_ * g_);
      float h = o_ * ftanh(c);
      ((float*)h4s)[j] = h;
      hs[(size_t)t * NF + j] = h;
    }
    __syncthreads();
  }
}

// ---------------- host launch ----------------

extern "C" void kernel_launch(void* const* d_in, const int* in_sizes, int n_in,
                              void* d_out, int out_size, void* d_ws, size_t ws_size,
                              hipStream_t stream) {
  const float* x     = (const float*)d_in[0];
  const void* edges  = d_in[1];
  const float* W1    = (const float*)d_in[2];
  const float* b1    = (const float*)d_in[3];
  const float* W2    = (const float*)d_in[4];
  const float* b2    = (const float*)d_in[5];
  const float* W_ih  = (const float*)d_in[6];
  const float* W_hh  = (const float*)d_in[7];
  const float* b_ih  = (const float*)d_in[8];
  const float* b_hh  = (const float*)d_in[9];
  const float* W_lin = (const float*)d_in[10];
  const float* b_lin = (const float*)d_in[11];
  float* out = (float*)d_out;

  const int N = in_sizes[0] / NF;  // 20000
  const int E = in_sizes[1] / 2;   // 640000
  const int OUTF = 64;

  char* base = (char*)d_ws;
  size_t off = 0;
  auto alloc = [&](size_t b) {
    char* p = base + off;
    off += (b + 255) & ~(size_t)255;
    return p;
  };
  float* dinv = (float*)alloc((size_t)N * 4);
  float* W1T  = (float*)alloc(128 * 128 * 4);
  float* W2T  = (float*)alloc(128 * 128 * 4);
  float* bsum = (float*)alloc(512 * 4);
  int*   flag = (int*)alloc(256);
  float* bufA = (float*)alloc((size_t)N * NF * 4);   // xw1 / xw2 (self-loop src)
  float* bufB = (float*)alloc((size_t)N * NF * 4);   // h1, later hs
  float* bufC = (float*)alloc((size_t)N * NF * 4);   // h2
  float* g_in = (float*)alloc((size_t)N * (size_t)G4 * 4);
  if (off > ws_size) return;  // workspace too small: fail loudly (poisoned out)

  // degree + norm
  k_fill<<<(N + 255) / 256, 256, 0, stream>>>(dinv, 1.0f, N);  // self loops
  k_detect_i64<<<1, 1, 0, stream>>>((const int*)edges, 1024, flag);
  k_count<<<(E + 255) / 256, 256, 0, stream>>>(edges, flag, dinv, E);
  k_rsqrt<<<(N + 255) / 256, 256, 0, stream>>>(dinv, N);
  k_t128<<<128, 128, 0, stream>>>(W1, W1T);
  k_t128<<<128, 128, 0, stream>>>(W2, W2T);
  k_add<<<2, 256, 0, stream>>>(b_ih, b_hh, bsum, 512);

  const int mg = (N + 63) / 64;

  // GCN layer 1
  gemm_bt<<<dim3(mg, 2), 256, 0, stream>>>(x, W1T, nullptr, bufA, N, NF, NF);
  hipMemsetAsync(bufB, 0, (size_t)N * NF * 4, stream);
  k_aggregate<<<(E + 7) / 8, 256, 0, stream>>>(bufA, edges, flag, dinv, bufB, E);
  k_finish<<<(N * 32 + 255) / 256, 256, 0, stream>>>(bufB, bufA, dinv, b1, N);

  // GCN layer 2
  gemm_bt<<<dim3(mg, 2), 256, 0, stream>>>(bufB, W2T, nullptr, bufA, N, NF, NF);
  hipMemsetAsync(bufC, 0, (size_t)N * NF * 4, stream);
  k_aggregate<<<(E + 7) / 8, 256, 0, stream>>>(bufA, edges, flag, dinv, bufC, E);
  k_finish<<<(N * 32 + 255) / 256, 256, 0, stream>>>(bufC, bufA, dinv, b2, N);

  // LSTM input precompute: g_in = h2 @ W_ih^T + (b_ih + b_hh)
  gemm_bt<<<dim3(mg, 8), 256, 0, stream>>>(bufC, W_ih, bsum, g_in, N, G4, NF);

  // sequential LSTM scan (hs -> bufB)
  k_lstm<<<1, 512, 0, stream>>>(g_in, W_hh, bufB, N);

  // final projection: out = hs @ W_lin^T + b_lin
  gemm_bt<<<dim3(mg, 1), 256, 0, stream>>>(bufB, W_lin, b_lin, out, N, OUTF, NF);
}

// Round 2
// 15919.569 us; speedup vs baseline: 1.0233x; 1.0233x over previous
//
#include <hip/hip_runtime.h>
#include <cstdint>

#define NF 128   // node feature / hidden width
#define G4 512   // 4*H gates

typedef float v2f __attribute__((ext_vector_type(2)));

__device__ __forceinline__ float frcp(float x) { return __builtin_amdgcn_rcpf(x); }
__device__ __forceinline__ float fsig(float x) { return frcp(1.f + __expf(-x)); }
__device__ __forceinline__ float ftanh(float x) {
  float e = __expf(2.f * x);
  return 1.f - 2.f * frcp(e + 1.f);
}

// DPP quad-perm lane exchanges (VALU, no LDS pipe, no barrier)
__device__ __forceinline__ float dpp_xor1(float x) {  // lane ^ 1 within quad
  int r = __builtin_amdgcn_update_dpp(0, __float_as_int(x), 0xB1, 0xF, 0xF, true);
  return __int_as_float(r);
}
__device__ __forceinline__ float dpp_xor2(float x) {  // lane ^ 2 within quad
  int r = __builtin_amdgcn_update_dpp(0, __float_as_int(x), 0x4E, 0xF, 0xF, true);
  return __int_as_float(r);
}

// ---------------- small utility kernels ----------------

__global__ void k_fill(float* p, float v, int n) {
  int i = blockIdx.x * blockDim.x + threadIdx.x;
  if (i < n) p[i] = v;
}

__global__ void k_detect_i64(const int* e, int npairs, int* flag) {
  int f = 1;
  for (int i = 1; i < 2 * npairs; i += 2)
    if (e[i] != 0) { f = 0; break; }
  *flag = f;
}

__device__ __forceinline__ int eidx(const void* edges, int i64, size_t pos) {
  if (i64) return (int)((const long long*)edges)[pos];
  return ((const int*)edges)[pos];
}

__global__ void k_count(const void* __restrict__ edges, const int* __restrict__ flag,
                        float* __restrict__ deg, int E) {
  int e = blockIdx.x * blockDim.x + threadIdx.x;
  if (e < E) {
    int d = eidx(edges, *flag, (size_t)E + e);
    unsafeAtomicAdd(&deg[d], 1.0f);
  }
}

__global__ void k_rsqrt(float* p, int n) {
  int i = blockIdx.x * blockDim.x + threadIdx.x;
  if (i < n) p[i] = rsqrtf(p[i]);
}

__global__ void k_t128(const float* __restrict__ in, float* __restrict__ out) {
  int n = blockIdx.x, k = threadIdx.x;
  out[n * 128 + k] = in[k * 128 + n];
}

__global__ void k_add(const float* a, const float* b, float* o, int n) {
  int i = blockIdx.x * blockDim.x + threadIdx.x;
  if (i < n) o[i] = a[i] + b[i];
}

// ---------------- GEMM: C[M,N] = A[M,K] @ B[N,K]^T (+bias) ----------------
__global__ __launch_bounds__(256)
void gemm_bt(const float* __restrict__ A, const float* __restrict__ B,
             const float* __restrict__ bias, float* __restrict__ C,
             int M, int N, int K) {
  __shared__ float As[32][68];
  __shared__ float Bs[32][68];
  const int bm = blockIdx.x * 64;
  const int bn = blockIdx.y * 64;
  const int tid = threadIdx.x;
  const int tm = (tid & 15) << 2;
  const int tn = (tid >> 4) << 2;
  float acc[4][4] = {};

  for (int k0 = 0; k0 < K; k0 += 32) {
#pragma unroll
    for (int l = 0; l < 2; ++l) {
      int idx = tid + l * 256;
      int row = idx >> 3;
      int k4 = (idx & 7) << 2;
      int ar = bm + row; ar = ar < M ? ar : M - 1;
      float4 av = *(const float4*)(A + (size_t)ar * K + k0 + k4);
      As[k4 + 0][row] = av.x; As[k4 + 1][row] = av.y;
      As[k4 + 2][row] = av.z; As[k4 + 3][row] = av.w;
      int br = bn + row; br = br < N ? br : N - 1;
      float4 bv = *(const float4*)(B + (size_t)br * K + k0 + k4);
      Bs[k4 + 0][row] = bv.x; Bs[k4 + 1][row] = bv.y;
      Bs[k4 + 2][row] = bv.z; Bs[k4 + 3][row] = bv.w;
    }
    __syncthreads();
#pragma unroll
    for (int kk = 0; kk < 32; ++kk) {
      float4 a = *(const float4*)&As[kk][tm];
      float4 b = *(const float4*)&Bs[kk][tn];
      float av[4] = {a.x, a.y, a.z, a.w};
      float bv[4] = {b.x, b.y, b.z, b.w};
#pragma unroll
      for (int i = 0; i < 4; ++i)
#pragma unroll
        for (int jj = 0; jj < 4; ++jj)
          acc[i][jj] = __builtin_fmaf(av[i], bv[jj], acc[i][jj]);
    }
    __syncthreads();
  }

  float4 bv4;
  if (bias) bv4 = *(const float4*)(bias + bn + tn);
  else bv4 = make_float4(0.f, 0.f, 0.f, 0.f);
#pragma unroll
  for (int i = 0; i < 4; ++i) {
    int row = bm + tm + i;
    if (row < M) {
      float4 v;
      v.x = acc[i][0] + bv4.x;
      v.y = acc[i][1] + bv4.y;
      v.z = acc[i][2] + bv4.z;
      v.w = acc[i][3] + bv4.w;
      *(float4*)(C + (size_t)row * N + bn + tn) = v;
    }
  }
}

// ---------------- GCN edge aggregation (atomic scatter) ----------------
__global__ __launch_bounds__(256)
void k_aggregate(const float* __restrict__ xw, const void* __restrict__ edges,
                 const int* __restrict__ flag, const float* __restrict__ dinv,
                 float* __restrict__ out, int E) {
  int e = blockIdx.x * 8 + (threadIdx.x >> 5);
  if (e >= E) return;
  int i64 = *flag;
  int s = eidx(edges, i64, e);
  int d = eidx(edges, i64, (size_t)E + e);
  float nrm = dinv[s] * dinv[d];
  int f4 = threadIdx.x & 31;
  float4 v = ((const float4*)xw)[(size_t)s * 32 + f4];
  float* op = out + (size_t)d * 128 + f4 * 4;
  unsafeAtomicAdd(op + 0, v.x * nrm);
  unsafeAtomicAdd(op + 1, v.y * nrm);
  unsafeAtomicAdd(op + 2, v.z * nrm);
  unsafeAtomicAdd(op + 3, v.w * nrm);
}

__global__ void k_finish(float* __restrict__ h, const float* __restrict__ xw,
                         const float* __restrict__ dinv, const float* __restrict__ b,
                         int N) {
  int i4 = blockIdx.x * blockDim.x + threadIdx.x;
  if (i4 >= N * 32) return;
  int n = i4 >> 5;
  int f4 = (i4 & 31) << 2;
  float di = dinv[n];
  float s = di * di;
  float4 ag = ((const float4*)h)[i4];
  float4 xv = ((const float4*)xw)[i4];
  float4 bv = *(const float4*)(b + f4);
  float4 r;
  r.x = fmaxf(__builtin_fmaf(xv.x, s, ag.x) + bv.x, 0.f);
  r.y = fmaxf(__builtin_fmaf(xv.y, s, ag.y) + bv.y, 0.f);
  r.z = fmaxf(__builtin_fmaf(xv.z, s, ag.z) + bv.z, 0.f);
  r.w = fmaxf(__builtin_fmaf(xv.w, s, ag.w) + bv.w, 0.f);
  ((float4*)h)[i4] = r;
}

// ---------------- sequential LSTM scan: 512 threads, quad-per-unit ----------------
// Quad 4u..4u+3 owns unit u: lane pos 0..3 computes gate rows u, u+128,
// u+256, u+384. Gate combine via DPP quad_perm (no barrier, no LDS).
// h double-buffered in LDS -> ONE barrier per step.
__global__ __launch_bounds__(512)
void k_lstm(const float* __restrict__ g_in, const float* __restrict__ W_hh,
            float* __restrict__ hs, int T) {
  const int t = threadIdx.x;
  const int q = t >> 2;        // unit 0..127
  const int pos = t & 3;       // gate slot: 0=i 1=f 2=g 3=o
  const int row = pos * 128 + q;

  __shared__ float hbuf[2][128];

  // W_hh row in VGPRs as 64 packed pairs (128 VGPRs)
  v2f w[64];
  {
    const float4* wr = (const float4*)(W_hh + (size_t)row * 128);
#pragma unroll
    for (int k = 0; k < 32; ++k) {
      float4 wv = wr[k];
      w[2 * k + 0] = (v2f){wv.x, wv.y};
      w[2 * k + 1] = (v2f){wv.z, wv.w};
    }
  }
  if (t < 128) hbuf[0][t] = 0.f;
  float c = 0.f;
  float gn = g_in[row];
  __syncthreads();

  int p = 0;
  const bool isg = (pos == 2);
  const bool sw1 = (pos & 1);
  const bool sw2 = (pos & 2);

  for (int step = 0; step < T; ++step) {
    float gcur = gn;
    size_t nb = (size_t)(step + 1 < T ? step + 1 : step) * G4;
    gn = g_in[nb + row];               // prefetch next step's input

    const float4* hb = (const float4*)hbuf[p];
    v2f a0 = {0.f, 0.f}, a1 = {0.f, 0.f}, a2 = {0.f, 0.f}, a3 = {0.f, 0.f};
#pragma unroll
    for (int k = 0; k < 32; k += 2) {
      float4 h0 = hb[k];
      float4 h1 = hb[k + 1];
      a0 = __builtin_elementwise_fma(w[2 * k + 0], (v2f){h0.x, h0.y}, a0);
      a1 = __builtin_elementwise_fma(w[2 * k + 1], (v2f){h0.z, h0.w}, a1);
      a2 = __builtin_elementwise_fma(w[2 * k + 2], (v2f){h1.x, h1.y}, a2);
      a3 = __builtin_elementwise_fma(w[2 * k + 3], (v2f){h1.z, h1.w}, a3);
    }
    v2f s01 = (a0 + a1) + (a2 + a3);
    float x = gcur + s01.x + s01.y;

    // activation: pos==2 -> tanh (as 2*sig(2x)-1), else sigmoid
    float xs = isg ? 2.f * x : x;
    float e = __expf(-xs);
    float r = frcp(1.f + e);
    float a = isg ? 2.f * r - 1.f : r;

    // quad butterfly: every lane collects all 4 gate activations
    float b = dpp_xor1(a);
    float c2 = dpp_xor2(a);
    float d2 = dpp_xor2(b);
    float p0 = sw1 ? b : a;
    float p1 = sw1 ? a : b;
    float p2 = sw1 ? d2 : c2;
    float p3 = sw1 ? c2 : d2;
    float i_ = sw2 ? p2 : p0;
    float f_ = sw2 ? p3 : p1;
    float g_ = sw2 ? p0 : p2;
    float o_ = sw2 ? p1 : p3;

    c = __builtin_fmaf(f_, c, i_ * g_);   // all 4 lanes redundantly
    float h = o_ * ftanh(c);

    p ^= 1;
    if (pos == 0) {
      hbuf[p][q] = h;
      hs[(size_t)step * NF + q] = h;
    }
    __syncthreads();
  }
}

// ---------------- host launch ----------------

extern "C" void kernel_launch(void* const* d_in, const int* in_sizes, int n_in,
                              void* d_out, int out_size, void* d_ws, size_t ws_size,
                              hipStream_t stream) {
  const float* x     = (const float*)d_in[0];
  const void* edges  = d_in[1];
  const float* W1    = (const float*)d_in[2];
  const float* b1    = (const float*)d_in[3];
  const float* W2    = (const float*)d_in[4];
  const float* b2    = (const float*)d_in[5];
  const float* W_ih  = (const float*)d_in[6];
  const float* W_hh  = (const float*)d_in[7];
  const float* b_ih  = (const float*)d_in[8];
  const float* b_hh  = (const float*)d_in[9];
  const float* W_lin = (const float*)d_in[10];
  const float* b_lin = (const float*)d_in[11];
  float* out = (float*)d_out;

  const int N = in_sizes[0] / NF;  // 20000
  const int E = in_sizes[1] / 2;   // 640000
  const int OUTF = 64;

  char* base = (char*)d_ws;
  size_t off = 0;
  auto alloc = [&](size_t b) {
    char* p = base + off;
    off += (b + 255) & ~(size_t)255;
    return p;
  };
  float* dinv = (float*)alloc((size_t)N * 4);
  float* W1T  = (float*)alloc(128 * 128 * 4);
  float* W2T  = (float*)alloc(128 * 128 * 4);
  float* bsum = (float*)alloc(512 * 4);
  int*   flag = (int*)alloc(256);
  float* bufA = (float*)alloc((size_t)N * NF * 4);
  float* bufB = (float*)alloc((size_t)N * NF * 4);
  float* bufC = (float*)alloc((size_t)N * NF * 4);
  float* g_in = (float*)alloc((size_t)N * (size_t)G4 * 4);
  if (off > ws_size) return;

  k_fill<<<(N + 255) / 256, 256, 0, stream>>>(dinv, 1.0f, N);
  k_detect_i64<<<1, 1, 0, stream>>>((const int*)edges, 1024, flag);
  k_count<<<(E + 255) / 256, 256, 0, stream>>>(edges, flag, dinv, E);
  k_rsqrt<<<(N + 255) / 256, 256, 0, stream>>>(dinv, N);
  k_t128<<<128, 128, 0, stream>>>(W1, W1T);
  k_t128<<<128, 128, 0, stream>>>(W2, W2T);
  k_add<<<2, 256, 0, stream>>>(b_ih, b_hh, bsum, 512);

  const int mg = (N + 63) / 64;

  gemm_bt<<<dim3(mg, 2), 256, 0, stream>>>(x, W1T, nullptr, bufA, N, NF, NF);
  hipMemsetAsync(bufB, 0, (size_t)N * NF * 4, stream);
  k_aggregate<<<(E + 7) / 8, 256, 0, stream>>>(bufA, edges, flag, dinv, bufB, E);
  k_finish<<<(N * 32 + 255) / 256, 256, 0, stream>>>(bufB, bufA, dinv, b1, N);

  gemm_bt<<<dim3(mg, 2), 256, 0, stream>>>(bufB, W2T, nullptr, bufA, N, NF, NF);
  hipMemsetAsync(bufC, 0, (size_t)N * NF * 4, stream);
  k_aggregate<<<(E + 7) / 8, 256, 0, stream>>>(bufA, edges, flag, dinv, bufC, E);
  k_finish<<<(N * 32 + 255) / 256, 256, 0, stream>>>(bufC, bufA, dinv, b2, N);

  gemm_bt<<<dim3(mg, 8), 256, 0, stream>>>(bufC, W_ih, bsum, g_in, N, G4, NF);

  k_lstm<<<1, 512, 0, stream>>>(g_in, W_hh, bufB, N);

  gemm_bt<<<dim3(mg, 1), 256, 0, stream>>>(bufB, W_lin, b_lin, out, N, OUTF, NF);
}

// Round 3
// 15911.986 us; speedup vs baseline: 1.0238x; 1.0005x over previous
//
#include <hip/hip_runtime.h>
#include <cstdint>

#define NF 128   // node feature / hidden width
#define G4 512   // 4*H gates

typedef float v2f __attribute__((ext_vector_type(2)));

__device__ __forceinline__ float frcp(float x) { return __builtin_amdgcn_rcpf(x); }
__device__ __forceinline__ float fsig(float x) { return frcp(1.f + __expf(-x)); }
__device__ __forceinline__ float ftanh(float x) {
  float e = __expf(2.f * x);
  return 1.f - 2.f * frcp(e + 1.f);
}

// DPP quad-perm lane exchanges (VALU, no LDS pipe, no barrier)
__device__ __forceinline__ float dpp_xor1(float x) {  // lane ^ 1 within quad
  int r = __builtin_amdgcn_update_dpp(0, __float_as_int(x), 0xB1, 0xF, 0xF, true);
  return __int_as_float(r);
}
__device__ __forceinline__ float dpp_xor2(float x) {  // lane ^ 2 within quad
  int r = __builtin_amdgcn_update_dpp(0, __float_as_int(x), 0x4E, 0xF, 0xF, true);
  return __int_as_float(r);
}

// ---------------- small utility kernels ----------------

__global__ void k_fill(float* p, float v, int n) {
  int i = blockIdx.x * blockDim.x + threadIdx.x;
  if (i < n) p[i] = v;
}

__global__ void k_detect_i64(const int* e, int npairs, int* flag) {
  int f = 1;
  for (int i = 1; i < 2 * npairs; i += 2)
    if (e[i] != 0) { f = 0; break; }
  *flag = f;
}

__device__ __forceinline__ int eidx(const void* edges, int i64, size_t pos) {
  if (i64) return (int)((const long long*)edges)[pos];
  return ((const int*)edges)[pos];
}

__global__ void k_count(const void* __restrict__ edges, const int* __restrict__ flag,
                        float* __restrict__ deg, int E) {
  int e = blockIdx.x * blockDim.x + threadIdx.x;
  if (e < E) {
    int d = eidx(edges, *flag, (size_t)E + e);
    unsafeAtomicAdd(&deg[d], 1.0f);
  }
}

__global__ void k_rsqrt(float* p, int n) {
  int i = blockIdx.x * blockDim.x + threadIdx.x;
  if (i < n) p[i] = rsqrtf(p[i]);
}

__global__ void k_t128(const float* __restrict__ in, float* __restrict__ out) {
  int n = blockIdx.x, k = threadIdx.x;
  out[n * 128 + k] = in[k * 128 + n];
}

__global__ void k_add(const float* a, const float* b, float* o, int n) {
  int i = blockIdx.x * blockDim.x + threadIdx.x;
  if (i < n) o[i] = a[i] + b[i];
}

// ---------------- GEMM: C[M,N] = A[M,K] @ B[N,K]^T (+bias) ----------------
__global__ __launch_bounds__(256)
void gemm_bt(const float* __restrict__ A, const float* __restrict__ B,
             const float* __restrict__ bias, float* __restrict__ C,
             int M, int N, int K) {
  __shared__ float As[32][68];
  __shared__ float Bs[32][68];
  const int bm = blockIdx.x * 64;
  const int bn = blockIdx.y * 64;
  const int tid = threadIdx.x;
  const int tm = (tid & 15) << 2;
  const int tn = (tid >> 4) << 2;
  float acc[4][4] = {};

  for (int k0 = 0; k0 < K; k0 += 32) {
#pragma unroll
    for (int l = 0; l < 2; ++l) {
      int idx = tid + l * 256;
      int row = idx >> 3;
      int k4 = (idx & 7) << 2;
      int ar = bm + row; ar = ar < M ? ar : M - 1;
      float4 av = *(const float4*)(A + (size_t)ar * K + k0 + k4);
      As[k4 + 0][row] = av.x; As[k4 + 1][row] = av.y;
      As[k4 + 2][row] = av.z; As[k4 + 3][row] = av.w;
      int br = bn + row; br = br < N ? br : N - 1;
      float4 bv = *(const float4*)(B + (size_t)br * K + k0 + k4);
      Bs[k4 + 0][row] = bv.x; Bs[k4 + 1][row] = bv.y;
      Bs[k4 + 2][row] = bv.z; Bs[k4 + 3][row] = bv.w;
    }
    __syncthreads();
#pragma unroll
    for (int kk = 0; kk < 32; ++kk) {
      float4 a = *(const float4*)&As[kk][tm];
      float4 b = *(const float4*)&Bs[kk][tn];
      float av[4] = {a.x, a.y, a.z, a.w};
      float bv[4] = {b.x, b.y, b.z, b.w};
#pragma unroll
      for (int i = 0; i < 4; ++i)
#pragma unroll
        for (int jj = 0; jj < 4; ++jj)
          acc[i][jj] = __builtin_fmaf(av[i], bv[jj], acc[i][jj]);
    }
    __syncthreads();
  }

  float4 bv4;
  if (bias) bv4 = *(const float4*)(bias + bn + tn);
  else bv4 = make_float4(0.f, 0.f, 0.f, 0.f);
#pragma unroll
  for (int i = 0; i < 4; ++i) {
    int row = bm + tm + i;
    if (row < M) {
      float4 v;
      v.x = acc[i][0] + bv4.x;
      v.y = acc[i][1] + bv4.y;
      v.z = acc[i][2] + bv4.z;
      v.w = acc[i][3] + bv4.w;
      *(float4*)(C + (size_t)row * N + bn + tn) = v;
    }
  }
}

// ---------------- GCN edge aggregation (atomic scatter) ----------------
__global__ __launch_bounds__(256)
void k_aggregate(const float* __restrict__ xw, const void* __restrict__ edges,
                 const int* __restrict__ flag, const float* __restrict__ dinv,
                 float* __restrict__ out, int E) {
  int e = blockIdx.x * 8 + (threadIdx.x >> 5);
  if (e >= E) return;
  int i64 = *flag;
  int s = eidx(edges, i64, e);
  int d = eidx(edges, i64, (size_t)E + e);
  float nrm = dinv[s] * dinv[d];
  int f4 = threadIdx.x & 31;
  float4 v = ((const float4*)xw)[(size_t)s * 32 + f4];
  float* op = out + (size_t)d * 128 + f4 * 4;
  unsafeAtomicAdd(op + 0, v.x * nrm);
  unsafeAtomicAdd(op + 1, v.y * nrm);
  unsafeAtomicAdd(op + 2, v.z * nrm);
  unsafeAtomicAdd(op + 3, v.w * nrm);
}

__global__ void k_finish(float* __restrict__ h, const float* __restrict__ xw,
                         const float* __restrict__ dinv, const float* __restrict__ b,
                         int N) {
  int i4 = blockIdx.x * blockDim.x + threadIdx.x;
  if (i4 >= N * 32) return;
  int n = i4 >> 5;
  int f4 = (i4 & 31) << 2;
  float di = dinv[n];
  float s = di * di;
  float4 ag = ((const float4*)h)[i4];
  float4 xv = ((const float4*)xw)[i4];
  float4 bv = *(const float4*)(b + f4);
  float4 r;
  r.x = fmaxf(__builtin_fmaf(xv.x, s, ag.x) + bv.x, 0.f);
  r.y = fmaxf(__builtin_fmaf(xv.y, s, ag.y) + bv.y, 0.f);
  r.z = fmaxf(__builtin_fmaf(xv.z, s, ag.z) + bv.z, 0.f);
  r.w = fmaxf(__builtin_fmaf(xv.w, s, ag.w) + bv.w, 0.f);
  ((float4*)h)[i4] = r;
}

// ---------------- sequential LSTM scan: 512 threads, quad-per-unit ----------------
// Quad 4u..4u+3 owns unit u: lane pos 0..3 computes gate rows u, u+128,
// u+256, u+384. Gate combine via DPP quad_perm (no barrier, no LDS).
// h double-buffered in LDS -> ONE barrier per step.
// __launch_bounds__(512, 2): 8 waves = 2 waves/EU -> 256-VGPR budget so the
// 128-VGPR weight row STAYS IN REGISTERS (R2 had VGPR_Count=80 => spilled).
__global__ __launch_bounds__(512, 2)
void k_lstm(const float* __restrict__ g_in, const float* __restrict__ W_hh,
            float* __restrict__ hs, int T) {
  const int t = threadIdx.x;
  const int q = t >> 2;        // unit 0..127
  const int pos = t & 3;       // gate slot: 0=i 1=f 2=g 3=o
  const int row = pos * 128 + q;

  __shared__ float hbuf[2][128];

  // W_hh row in VGPRs as 64 packed pairs (128 VGPRs)
  v2f w[64];
  {
    const float4* wr = (const float4*)(W_hh + (size_t)row * 128);
#pragma unroll
    for (int k = 0; k < 32; ++k) {
      float4 wv = wr[k];
      w[2 * k + 0] = (v2f){wv.x, wv.y};
      w[2 * k + 1] = (v2f){wv.z, wv.w};
    }
  }
  if (t < 128) hbuf[0][t] = 0.f;
  float c = 0.f;
  float gn = g_in[row];
  __syncthreads();

  int p = 0;
  const bool isg = (pos == 2);
  const bool sw1 = (pos & 1);
  const bool sw2 = (pos & 2);

  for (int step = 0; step < T; ++step) {
    float gcur = gn;
    size_t nb = (size_t)(step + 1 < T ? step + 1 : step) * G4;
    gn = g_in[nb + row];               // prefetch next step's input

    const float4* hb = (const float4*)hbuf[p];
    v2f a0 = {0.f, 0.f}, a1 = {0.f, 0.f}, a2 = {0.f, 0.f}, a3 = {0.f, 0.f};
#pragma unroll
    for (int k = 0; k < 32; k += 2) {
      float4 h0 = hb[k];
      float4 h1 = hb[k + 1];
      a0 = __builtin_elementwise_fma(w[2 * k + 0], (v2f){h0.x, h0.y}, a0);
      a1 = __builtin_elementwise_fma(w[2 * k + 1], (v2f){h0.z, h0.w}, a1);
      a2 = __builtin_elementwise_fma(w[2 * k + 2], (v2f){h1.x, h1.y}, a2);
      a3 = __builtin_elementwise_fma(w[2 * k + 3], (v2f){h1.z, h1.w}, a3);
    }
    v2f s01 = (a0 + a1) + (a2 + a3);
    float x = gcur + s01.x + s01.y;

    // activation: pos==2 -> tanh (as 2*sig(2x)-1), else sigmoid
    float xs = isg ? 2.f * x : x;
    float e = __expf(-xs);
    float r = frcp(1.f + e);
    float a = isg ? 2.f * r - 1.f : r;

    // quad butterfly: every lane collects all 4 gate activations
    float b = dpp_xor1(a);
    float c2 = dpp_xor2(a);
    float d2 = dpp_xor2(b);
    float p0 = sw1 ? b : a;
    float p1 = sw1 ? a : b;
    float p2 = sw1 ? d2 : c2;
    float p3 = sw1 ? c2 : d2;
    float i_ = sw2 ? p2 : p0;
    float f_ = sw2 ? p3 : p1;
    float g_ = sw2 ? p0 : p2;
    float o_ = sw2 ? p1 : p3;

    c = __builtin_fmaf(f_, c, i_ * g_);   // all 4 lanes redundantly
    float h = o_ * ftanh(c);

    p ^= 1;
    if (pos == 0) {
      hbuf[p][q] = h;
      hs[(size_t)step * NF + q] = h;
    }
    __syncthreads();
  }
}

// ---------------- host launch ----------------

extern "C" void kernel_launch(void* const* d_in, const int* in_sizes, int n_in,
                              void* d_out, int out_size, void* d_ws, size_t ws_size,
                              hipStream_t stream) {
  const float* x     = (const float*)d_in[0];
  const void* edges  = d_in[1];
  const float* W1    = (const float*)d_in[2];
  const float* b1    = (const float*)d_in[3];
  const float* W2    = (const float*)d_in[4];
  const float* b2    = (const float*)d_in[5];
  const float* W_ih  = (const float*)d_in[6];
  const float* W_hh  = (const float*)d_in[7];
  const float* b_ih  = (const float*)d_in[8];
  const float* b_hh  = (const float*)d_in[9];
  const float* W_lin = (const float*)d_in[10];
  const float* b_lin = (const float*)d_in[11];
  float* out = (float*)d_out;

  const int N = in_sizes[0] / NF;  // 20000
  const int E = in_sizes[1] / 2;   // 640000
  const int OUTF = 64;

  char* base = (char*)d_ws;
  size_t off = 0;
  auto alloc = [&](size_t b) {
    char* p = base + off;
    off += (b + 255) & ~(size_t)255;
    return p;
  };
  float* dinv = (float*)alloc((size_t)N * 4);
  float* W1T  = (float*)alloc(128 * 128 * 4);
  float* W2T  = (float*)alloc(128 * 128 * 4);
  float* bsum = (float*)alloc(512 * 4);
  int*   flag = (int*)alloc(256);
  float* bufA = (float*)alloc((size_t)N * NF * 4);
  float* bufB = (float*)alloc((size_t)N * NF * 4);
  float* bufC = (float*)alloc((size_t)N * NF * 4);
  float* g_in = (float*)alloc((size_t)N * (size_t)G4 * 4);
  if (off > ws_size) return;

  k_fill<<<(N + 255) / 256, 256, 0, stream>>>(dinv, 1.0f, N);
  k_detect_i64<<<1, 1, 0, stream>>>((const int*)edges, 1024, flag);
  k_count<<<(E + 255) / 256, 256, 0, stream>>>(edges, flag, dinv, E);
  k_rsqrt<<<(N + 255) / 256, 256, 0, stream>>>(dinv, N);
  k_t128<<<128, 128, 0, stream>>>(W1, W1T);
  k_t128<<<128, 128, 0, stream>>>(W2, W2T);
  k_add<<<2, 256, 0, stream>>>(b_ih, b_hh, bsum, 512);

  const int mg = (N + 63) / 64;

  gemm_bt<<<dim3(mg, 2), 256, 0, stream>>>(x, W1T, nullptr, bufA, N, NF, NF);
  hipMemsetAsync(bufB, 0, (size_t)N * NF * 4, stream);
  k_aggregate<<<(E + 7) / 8, 256, 0, stream>>>(bufA, edges, flag, dinv, bufB, E);
  k_finish<<<(N * 32 + 255) / 256, 256, 0, stream>>>(bufB, bufA, dinv, b1, N);

  gemm_bt<<<dim3(mg, 2), 256, 0, stream>>>(bufB, W2T, nullptr, bufA, N, NF, NF);
  hipMemsetAsync(bufC, 0, (size_t)N * NF * 4, stream);
  k_aggregate<<<(E + 7) / 8, 256, 0, stream>>>(bufA, edges, flag, dinv, bufC, E);
  k_finish<<<(N * 32 + 255) / 256, 256, 0, stream>>>(bufC, bufA, dinv, b2, N);

  gemm_bt<<<dim3(mg, 8), 256, 0, stream>>>(bufC, W_ih, bsum, g_in, N, G4, NF);

  k_lstm<<<1, 512, 0, stream>>>(g_in, W_hh, bufB, N);

  gemm_bt<<<dim3(mg, 1), 256, 0, stream>>>(bufB, W_lin, b_lin, out, N, OUTF, NF);
}

// Round 4
// 13660.469 us; speedup vs baseline: 1.1925x; 1.1648x over previous
//
#include <hip/hip_runtime.h>
#include <cstdint>

#define NF 128   // node feature / hidden width
#define G4 512   // 4*H gates

typedef float v2f __attribute__((ext_vector_type(2)));

__device__ __forceinline__ float frcp(float x) { return __builtin_amdgcn_rcpf(x); }
__device__ __forceinline__ float ftanh(float x) {
  float e = __expf(2.f * x);
  return 1.f - 2.f * frcp(e + 1.f);
}

// DPP quad-perm lane exchanges (VALU, no LDS pipe, no barrier)
__device__ __forceinline__ float dpp_xor1(float x) {  // lane ^ 1 within quad
  int r = __builtin_amdgcn_update_dpp(0, __float_as_int(x), 0xB1, 0xF, 0xF, true);
  return __int_as_float(r);
}
__device__ __forceinline__ float dpp_xor2(float x) {  // lane ^ 2 within quad
  int r = __builtin_amdgcn_update_dpp(0, __float_as_int(x), 0x4E, 0xF, 0xF, true);
  return __int_as_float(r);
}

// ---------------- small utility kernels ----------------

__global__ void k_fill(float* p, float v, int n) {
  int i = blockIdx.x * blockDim.x + threadIdx.x;
  if (i < n) p[i] = v;
}

__global__ void k_detect_i64(const int* e, int npairs, int* flag) {
  int f = 1;
  for (int i = 1; i < 2 * npairs; i += 2)
    if (e[i] != 0) { f = 0; break; }
  *flag = f;
}

__device__ __forceinline__ int eidx(const void* edges, int i64, size_t pos) {
  if (i64) return (int)((const long long*)edges)[pos];
  return ((const int*)edges)[pos];
}

__global__ void k_count(const void* __restrict__ edges, const int* __restrict__ flag,
                        float* __restrict__ deg, int E) {
  int e = blockIdx.x * blockDim.x + threadIdx.x;
  if (e < E) {
    int d = eidx(edges, *flag, (size_t)E + e);
    unsafeAtomicAdd(&deg[d], 1.0f);
  }
}

__global__ void k_rsqrt(float* p, int n) {
  int i = blockIdx.x * blockDim.x + threadIdx.x;
  if (i < n) p[i] = rsqrtf(p[i]);
}

__global__ void k_t128(const float* __restrict__ in, float* __restrict__ out) {
  int n = blockIdx.x, k = threadIdx.x;
  out[n * 128 + k] = in[k * 128 + n];
}

__global__ void k_add(const float* a, const float* b, float* o, int n) {
  int i = blockIdx.x * blockDim.x + threadIdx.x;
  if (i < n) o[i] = a[i] + b[i];
}

// Quad-transpose W_hh for the LSTM: lane t=4u+p owns, for each gate g,
// columns [32p, 32p+32) of row g*128+u.  wp[t][g*32+k] = W[g*128+u][32p+k].
__global__ void k_wprep(const float* __restrict__ W, float* __restrict__ wp) {
  int t = blockIdx.x;        // 0..511
  int j = threadIdx.x;       // 0..127
  int u = t >> 2, p = t & 3;
  int g = j >> 5, k = j & 31;
  wp[(size_t)t * 128 + j] = W[(size_t)(g * 128 + u) * 128 + 32 * p + k];
}

// ---------------- GEMM: C[M,N] = A[M,K] @ B[N,K]^T (+bias) ----------------
__global__ __launch_bounds__(256)
void gemm_bt(const float* __restrict__ A, const float* __restrict__ B,
             const float* __restrict__ bias, float* __restrict__ C,
             int M, int N, int K) {
  __shared__ float As[32][68];
  __shared__ float Bs[32][68];
  const int bm = blockIdx.x * 64;
  const int bn = blockIdx.y * 64;
  const int tid = threadIdx.x;
  const int tm = (tid & 15) << 2;
  const int tn = (tid >> 4) << 2;
  float acc[4][4] = {};

  for (int k0 = 0; k0 < K; k0 += 32) {
#pragma unroll
    for (int l = 0; l < 2; ++l) {
      int idx = tid + l * 256;
      int row = idx >> 3;
      int k4 = (idx & 7) << 2;
      int ar = bm + row; ar = ar < M ? ar : M - 1;
      float4 av = *(const float4*)(A + (size_t)ar * K + k0 + k4);
      As[k4 + 0][row] = av.x; As[k4 + 1][row] = av.y;
      As[k4 + 2][row] = av.z; As[k4 + 3][row] = av.w;
      int br = bn + row; br = br < N ? br : N - 1;
      float4 bv = *(const float4*)(B + (size_t)br * K + k0 + k4);
      Bs[k4 + 0][row] = bv.x; Bs[k4 + 1][row] = bv.y;
      Bs[k4 + 2][row] = bv.z; Bs[k4 + 3][row] = bv.w;
    }
    __syncthreads();
#pragma unroll
    for (int kk = 0; kk < 32; ++kk) {
      float4 a = *(const float4*)&As[kk][tm];
      float4 b = *(const float4*)&Bs[kk][tn];
      float av[4] = {a.x, a.y, a.z, a.w};
      float bv[4] = {b.x, b.y, b.z, b.w};
#pragma unroll
      for (int i = 0; i < 4; ++i)
#pragma unroll
        for (int jj = 0; jj < 4; ++jj)
          acc[i][jj] = __builtin_fmaf(av[i], bv[jj], acc[i][jj]);
    }
    __syncthreads();
  }

  float4 bv4;
  if (bias) bv4 = *(const float4*)(bias + bn + tn);
  else bv4 = make_float4(0.f, 0.f, 0.f, 0.f);
#pragma unroll
  for (int i = 0; i < 4; ++i) {
    int row = bm + tm + i;
    if (row < M) {
      float4 v;
      v.x = acc[i][0] + bv4.x;
      v.y = acc[i][1] + bv4.y;
      v.z = acc[i][2] + bv4.z;
      v.w = acc[i][3] + bv4.w;
      *(float4*)(C + (size_t)row * N + bn + tn) = v;
    }
  }
}

// ---------------- GCN edge aggregation (atomic scatter) ----------------
__global__ __launch_bounds__(256)
void k_aggregate(const float* __restrict__ xw, const void* __restrict__ edges,
                 const int* __restrict__ flag, const float* __restrict__ dinv,
                 float* __restrict__ out, int E) {
  int e = blockIdx.x * 8 + (threadIdx.x >> 5);
  if (e >= E) return;
  int i64 = *flag;
  int s = eidx(edges, i64, e);
  int d = eidx(edges, i64, (size_t)E + e);
  float nrm = dinv[s] * dinv[d];
  int f4 = threadIdx.x & 31;
  float4 v = ((const float4*)xw)[(size_t)s * 32 + f4];
  float* op = out + (size_t)d * 128 + f4 * 4;
  unsafeAtomicAdd(op + 0, v.x * nrm);
  unsafeAtomicAdd(op + 1, v.y * nrm);
  unsafeAtomicAdd(op + 2, v.z * nrm);
  unsafeAtomicAdd(op + 3, v.w * nrm);
}

__global__ void k_finish(float* __restrict__ h, const float* __restrict__ xw,
                         const float* __restrict__ dinv, const float* __restrict__ b,
                         int N) {
  int i4 = blockIdx.x * blockDim.x + threadIdx.x;
  if (i4 >= N * 32) return;
  int n = i4 >> 5;
  int f4 = (i4 & 31) << 2;
  float di = dinv[n];
  float s = di * di;
  float4 ag = ((const float4*)h)[i4];
  float4 xv = ((const float4*)xw)[i4];
  float4 bv = *(const float4*)(b + f4);
  float4 r;
  r.x = fmaxf(__builtin_fmaf(xv.x, s, ag.x) + bv.x, 0.f);
  r.y = fmaxf(__builtin_fmaf(xv.y, s, ag.y) + bv.y, 0.f);
  r.z = fmaxf(__builtin_fmaf(xv.z, s, ag.z) + bv.z, 0.f);
  r.w = fmaxf(__builtin_fmaf(xv.w, s, ag.w) + bv.w, 0.f);
  ((float4*)h)[i4] = r;
}

// ---------------- sequential LSTM scan ----------------
// 512 threads, quad 4u..4u+3 owns unit u.  Lane p of the quad:
//  - holds, for each gate g in {i,f,g,o}, weights W[g*128+u][32p..32p+31]
//    (quad-transposed by k_wprep) -> 128 weight floats in VGPRs.
//  - reads only ITS quarter of h (8 x ds_read_b128, skewed layout so the
//    4 quarter address-groups hit disjoint LDS banks).
//  - computes 4 partial dots, then a 2-round DPP quad butterfly-reduce
//    gives the full preactivation of gate p; activation; DPP gather of all
//    4 activations; redundant c/h update.  ONE barrier per step.
// amdgpu_waves_per_eu(2,2): clamps the occupancy TARGET to 2 waves/EU
// (256-VGPR budget) so the 128 weight VGPRs stay resident -- R2/R3 showed
// the scheduler otherwise remats the weight loads into the loop (VGPR=80).
__global__ __launch_bounds__(512)
__attribute__((amdgpu_waves_per_eu(2, 2)))
void k_lstm(const float* __restrict__ g_in, const float* __restrict__ wp,
            float* __restrict__ hs, int T) {
  const int t = threadIdx.x;
  const int q = t >> 2;        // unit 0..127
  const int pos = t & 3;       // gate slot: 0=i 1=f 2=g 3=o
  const int row = pos * 128 + q;

  __shared__ __align__(16) float hbuf[2][144];   // skew: h[q] at q + 4*(q>>5)

  // 128 weight floats in VGPRs as 64 packed pairs
  v2f wq[64];
  {
    const float4* wr = (const float4*)(wp + (size_t)t * 128);
#pragma unroll
    for (int k = 0; k < 32; ++k) {
      float4 wv = wr[k];
      wq[2 * k + 0] = (v2f){wv.x, wv.y};
      wq[2 * k + 1] = (v2f){wv.z, wv.w};
    }
  }
  if (t < 144) { hbuf[0][t] = 0.f; hbuf[1][t] = 0.f; }
  float c = 0.f;
  float gn = g_in[row];
  __syncthreads();

  int pb = 0;
  const bool isg = (pos == 2);
  const bool sw1 = (pos & 1);
  const bool sw2 = (pos & 2) != 0;

  for (int step = 0; step < T; ++step) {
    float gcur = gn;
    size_t nb = (size_t)(step + 1 < T ? step + 1 : step) * G4;
    gn = g_in[nb + row];               // prefetch next step's input

    const float4* hb = (const float4*)&hbuf[pb][36 * pos];
    v2f a0 = {0.f, 0.f}, a1 = {0.f, 0.f}, a2 = {0.f, 0.f}, a3 = {0.f, 0.f};
#pragma unroll
    for (int jj = 0; jj < 8; ++jj) {
      float4 hv = hb[jj];
      v2f hlo = (v2f){hv.x, hv.y};
      v2f hhi = (v2f){hv.z, hv.w};
      a0 = __builtin_elementwise_fma(wq[0 * 16 + 2 * jj], hlo, a0);
      a0 = __builtin_elementwise_fma(wq[0 * 16 + 2 * jj + 1], hhi, a0);
      a1 = __builtin_elementwise_fma(wq[1 * 16 + 2 * jj], hlo, a1);
      a1 = __builtin_elementwise_fma(wq[1 * 16 + 2 * jj + 1], hhi, a1);
      a2 = __builtin_elementwise_fma(wq[2 * 16 + 2 * jj], hlo, a2);
      a2 = __builtin_elementwise_fma(wq[2 * 16 + 2 * jj + 1], hhi, a2);
      a3 = __builtin_elementwise_fma(wq[3 * 16 + 2 * jj], hlo, a3);
      a3 = __builtin_elementwise_fma(wq[3 * 16 + 2 * jj + 1], hhi, a3);
    }
    float s0 = a0.x + a0.y;
    float s1 = a1.x + a1.y;
    float s2 = a2.x + a2.y;
    float s3 = a3.x + a3.y;

    // quad butterfly-REDUCE: lane p ends with gate p's full preactivation
    float send_lo = sw1 ? s0 : s1;
    float send_hi = sw1 ? s2 : s3;
    float keep_lo = sw1 ? s1 : s0;
    float keep_hi = sw1 ? s3 : s2;
    float r_lo = keep_lo + dpp_xor1(send_lo);   // gate (p&1)
    float r_hi = keep_hi + dpp_xor1(send_hi);   // gate (p&1)+2
    float send2 = sw2 ? r_lo : r_hi;
    float keep2 = sw2 ? r_hi : r_lo;
    float x = keep2 + dpp_xor2(send2) + gcur;   // gate p total

    // activation: pos==2 -> tanh (as 2*sig(2x)-1), else sigmoid
    float xs = isg ? 2.f * x : x;
    float e = __expf(-xs);
    float r = frcp(1.f + e);
    float a = isg ? 2.f * r - 1.f : r;

    // quad butterfly-GATHER: every lane collects all 4 gate activations
    float b = dpp_xor1(a);
    float c2 = dpp_xor2(a);
    float d2 = dpp_xor2(b);
    float p0 = sw1 ? b : a;
    float p1 = sw1 ? a : b;
    float p2 = sw1 ? d2 : c2;
    float p3 = sw1 ? c2 : d2;
    float i_ = sw2 ? p2 : p0;
    float f_ = sw2 ? p3 : p1;
    float g_ = sw2 ? p0 : p2;
    float o_ = sw2 ? p1 : p3;

    c = __builtin_fmaf(f_, c, i_ * g_);   // all 4 lanes redundantly
    float h = o_ * ftanh(c);

    pb ^= 1;
    if (pos == 0) {
      hbuf[pb][q + ((q >> 5) << 2)] = h;
      hs[(size_t)step * NF + q] = h;
    }
    __syncthreads();
  }
}

// ---------------- host launch ----------------

extern "C" void kernel_launch(void* const* d_in, const int* in_sizes, int n_in,
                              void* d_out, int out_size, void* d_ws, size_t ws_size,
                              hipStream_t stream) {
  const float* x     = (const float*)d_in[0];
  const void* edges  = d_in[1];
  const float* W1    = (const float*)d_in[2];
  const float* b1    = (const float*)d_in[3];
  const float* W2    = (const float*)d_in[4];
  const float* b2    = (const float*)d_in[5];
  const float* W_ih  = (const float*)d_in[6];
  const float* W_hh  = (const float*)d_in[7];
  const float* b_ih  = (const float*)d_in[8];
  const float* b_hh  = (const float*)d_in[9];
  const float* W_lin = (const float*)d_in[10];
  const float* b_lin = (const float*)d_in[11];
  float* out = (float*)d_out;

  const int N = in_sizes[0] / NF;  // 20000
  const int E = in_sizes[1] / 2;   // 640000
  const int OUTF = 64;

  char* base = (char*)d_ws;
  size_t off = 0;
  auto alloc = [&](size_t b) {
    char* p = base + off;
    off += (b + 255) & ~(size_t)255;
    return p;
  };
  float* dinv = (float*)alloc((size_t)N * 4);
  float* W1T  = (float*)alloc(128 * 128 * 4);
  float* W2T  = (float*)alloc(128 * 128 * 4);
  float* wp   = (float*)alloc(512 * 128 * 4);
  float* bsum = (float*)alloc(512 * 4);
  int*   flag = (int*)alloc(256);
  float* bufA = (float*)alloc((size_t)N * NF * 4);
  float* bufB = (float*)alloc((size_t)N * NF * 4);
  float* bufC = (float*)alloc((size_t)N * NF * 4);
  float* g_in = (float*)alloc((size_t)N * (size_t)G4 * 4);
  if (off > ws_size) return;

  k_fill<<<(N + 255) / 256, 256, 0, stream>>>(dinv, 1.0f, N);
  k_detect_i64<<<1, 1, 0, stream>>>((const int*)edges, 1024, flag);
  k_count<<<(E + 255) / 256, 256, 0, stream>>>(edges, flag, dinv, E);
  k_rsqrt<<<(N + 255) / 256, 256, 0, stream>>>(dinv, N);
  k_t128<<<128, 128, 0, stream>>>(W1, W1T);
  k_t128<<<128, 128, 0, stream>>>(W2, W2T);
  k_wprep<<<512, 128, 0, stream>>>(W_hh, wp);
  k_add<<<2, 256, 0, stream>>>(b_ih, b_hh, bsum, 512);

  const int mg = (N + 63) / 64;

  gemm_bt<<<dim3(mg, 2), 256, 0, stream>>>(x, W1T, nullptr, bufA, N, NF, NF);
  hipMemsetAsync(bufB, 0, (size_t)N * NF * 4, stream);
  k_aggregate<<<(E + 7) / 8, 256, 0, stream>>>(bufA, edges, flag, dinv, bufB, E);
  k_finish<<<(N * 32 + 255) / 256, 256, 0, stream>>>(bufB, bufA, dinv, b1, N);

  gemm_bt<<<dim3(mg, 2), 256, 0, stream>>>(bufB, W2T, nullptr, bufA, N, NF, NF);
  hipMemsetAsync(bufC, 0, (size_t)N * NF * 4, stream);
  k_aggregate<<<(E + 7) / 8, 256, 0, stream>>>(bufA, edges, flag, dinv, bufC, E);
  k_finish<<<(N * 32 + 255) / 256, 256, 0, stream>>>(bufC, bufA, dinv, b2, N);

  gemm_bt<<<dim3(mg, 8), 256, 0, stream>>>(bufC, W_ih, bsum, g_in, N, G4, NF);

  k_lstm<<<1, 512, 0, stream>>>(g_in, wp, bufB, N);

  gemm_bt<<<dim3(mg, 1), 256, 0, stream>>>(bufB, W_lin, b_lin, out, N, OUTF, NF);
}

// Round 5
// 13625.461 us; speedup vs baseline: 1.1956x; 1.0026x over previous
//
#include <hip/hip_runtime.h>
#include <cstdint>

#define NF 128   // node feature / hidden width
#define G4 512   // 4*H gates

typedef float v2f __attribute__((ext_vector_type(2)));

__device__ __forceinline__ float frcp(float x) { return __builtin_amdgcn_rcpf(x); }
__device__ __forceinline__ float ftanh(float x) {
  float e = __expf(2.f * x);
  return 1.f - 2.f * frcp(e + 1.f);
}

// DPP quad-perm lane exchanges (VALU, no LDS pipe, no barrier)
__device__ __forceinline__ float dpp_xor1(float x) {  // lane ^ 1 within quad
  int r = __builtin_amdgcn_update_dpp(0, __float_as_int(x), 0xB1, 0xF, 0xF, true);
  return __int_as_float(r);
}
__device__ __forceinline__ float dpp_xor2(float x) {  // lane ^ 2 within quad
  int r = __builtin_amdgcn_update_dpp(0, __float_as_int(x), 0x4E, 0xF, 0xF, true);
  return __int_as_float(r);
}

// ---------------- small utility kernels ----------------

__global__ void k_fill(float* p, float v, int n) {
  int i = blockIdx.x * blockDim.x + threadIdx.x;
  if (i < n) p[i] = v;
}

__global__ void k_detect_i64(const int* e, int npairs, int* flag) {
  int f = 1;
  for (int i = 1; i < 2 * npairs; i += 2)
    if (e[i] != 0) { f = 0; break; }
  *flag = f;
}

__device__ __forceinline__ int eidx(const void* edges, int i64, size_t pos) {
  if (i64) return (int)((const long long*)edges)[pos];
  return ((const int*)edges)[pos];
}

__global__ void k_count(const void* __restrict__ edges, const int* __restrict__ flag,
                        float* __restrict__ deg, int E) {
  int e = blockIdx.x * blockDim.x + threadIdx.x;
  if (e < E) {
    int d = eidx(edges, *flag, (size_t)E + e);
    unsafeAtomicAdd(&deg[d], 1.0f);
  }
}

__global__ void k_rsqrt(float* p, int n) {
  int i = blockIdx.x * blockDim.x + threadIdx.x;
  if (i < n) p[i] = rsqrtf(p[i]);
}

__global__ void k_t128(const float* __restrict__ in, float* __restrict__ out) {
  int n = blockIdx.x, k = threadIdx.x;
  out[n * 128 + k] = in[k * 128 + n];
}

__global__ void k_add(const float* a, const float* b, float* o, int n) {
  int i = blockIdx.x * blockDim.x + threadIdx.x;
  if (i < n) o[i] = a[i] + b[i];
}

// Quad-transpose W_hh for the LSTM: lane t=4u+p owns, for each gate g,
// columns [32p, 32p+32) of row g*128+u.  wp[t][g*32+k] = W[g*128+u][32p+k].
__global__ void k_wprep(const float* __restrict__ W, float* __restrict__ wp) {
  int t = blockIdx.x;        // 0..511
  int j = threadIdx.x;       // 0..127
  int u = t >> 2, p = t & 3;
  int g = j >> 5, k = j & 31;
  wp[(size_t)t * 128 + j] = W[(size_t)(g * 128 + u) * 128 + 32 * p + k];
}

// ---------------- GEMM: C[M,N] = A[M,K] @ B[N,K]^T (+bias) ----------------
__global__ __launch_bounds__(256)
void gemm_bt(const float* __restrict__ A, const float* __restrict__ B,
             const float* __restrict__ bias, float* __restrict__ C,
             int M, int N, int K) {
  __shared__ float As[32][68];
  __shared__ float Bs[32][68];
  const int bm = blockIdx.x * 64;
  const int bn = blockIdx.y * 64;
  const int tid = threadIdx.x;
  const int tm = (tid & 15) << 2;
  const int tn = (tid >> 4) << 2;
  float acc[4][4] = {};

  for (int k0 = 0; k0 < K; k0 += 32) {
#pragma unroll
    for (int l = 0; l < 2; ++l) {
      int idx = tid + l * 256;
      int row = idx >> 3;
      int k4 = (idx & 7) << 2;
      int ar = bm + row; ar = ar < M ? ar : M - 1;
      float4 av = *(const float4*)(A + (size_t)ar * K + k0 + k4);
      As[k4 + 0][row] = av.x; As[k4 + 1][row] = av.y;
      As[k4 + 2][row] = av.z; As[k4 + 3][row] = av.w;
      int br = bn + row; br = br < N ? br : N - 1;
      float4 bv = *(const float4*)(B + (size_t)br * K + k0 + k4);
      Bs[k4 + 0][row] = bv.x; Bs[k4 + 1][row] = bv.y;
      Bs[k4 + 2][row] = bv.z; Bs[k4 + 3][row] = bv.w;
    }
    __syncthreads();
#pragma unroll
    for (int kk = 0; kk < 32; ++kk) {
      float4 a = *(const float4*)&As[kk][tm];
      float4 b = *(const float4*)&Bs[kk][tn];
      float av[4] = {a.x, a.y, a.z, a.w};
      float bv[4] = {b.x, b.y, b.z, b.w};
#pragma unroll
      for (int i = 0; i < 4; ++i)
#pragma unroll
        for (int jj = 0; jj < 4; ++jj)
          acc[i][jj] = __builtin_fmaf(av[i], bv[jj], acc[i][jj]);
    }
    __syncthreads();
  }

  float4 bv4;
  if (bias) bv4 = *(const float4*)(bias + bn + tn);
  else bv4 = make_float4(0.f, 0.f, 0.f, 0.f);
#pragma unroll
  for (int i = 0; i < 4; ++i) {
    int row = bm + tm + i;
    if (row < M) {
      float4 v;
      v.x = acc[i][0] + bv4.x;
      v.y = acc[i][1] + bv4.y;
      v.z = acc[i][2] + bv4.z;
      v.w = acc[i][3] + bv4.w;
      *(float4*)(C + (size_t)row * N + bn + tn) = v;
    }
  }
}

// ---------------- GCN edge aggregation (atomic scatter) ----------------
__global__ __launch_bounds__(256)
void k_aggregate(const float* __restrict__ xw, const void* __restrict__ edges,
                 const int* __restrict__ flag, const float* __restrict__ dinv,
                 float* __restrict__ out, int E) {
  int e = blockIdx.x * 8 + (threadIdx.x >> 5);
  if (e >= E) return;
  int i64 = *flag;
  int s = eidx(edges, i64, e);
  int d = eidx(edges, i64, (size_t)E + e);
  float nrm = dinv[s] * dinv[d];
  int f4 = threadIdx.x & 31;
  float4 v = ((const float4*)xw)[(size_t)s * 32 + f4];
  float* op = out + (size_t)d * 128 + f4 * 4;
  unsafeAtomicAdd(op + 0, v.x * nrm);
  unsafeAtomicAdd(op + 1, v.y * nrm);
  unsafeAtomicAdd(op + 2, v.z * nrm);
  unsafeAtomicAdd(op + 3, v.w * nrm);
}

__global__ void k_finish(float* __restrict__ h, const float* __restrict__ xw,
                         const float* __restrict__ dinv, const float* __restrict__ b,
                         int N) {
  int i4 = blockIdx.x * blockDim.x + threadIdx.x;
  if (i4 >= N * 32) return;
  int n = i4 >> 5;
  int f4 = (i4 & 31) << 2;
  float di = dinv[n];
  float s = di * di;
  float4 ag = ((const float4*)h)[i4];
  float4 xv = ((const float4*)xw)[i4];
  float4 bv = *(const float4*)(b + f4);
  float4 r;
  r.x = fmaxf(__builtin_fmaf(xv.x, s, ag.x) + bv.x, 0.f);
  r.y = fmaxf(__builtin_fmaf(xv.y, s, ag.y) + bv.y, 0.f);
  r.z = fmaxf(__builtin_fmaf(xv.z, s, ag.z) + bv.z, 0.f);
  r.w = fmaxf(__builtin_fmaf(xv.w, s, ag.w) + bv.w, 0.f);
  ((float4*)h)[i4] = r;
}

// ---------------- sequential LSTM scan ----------------
// 512 threads, quad 4u..4u+3 owns unit u (see R4 comments for data layout).
// LDS OCCUPANCY CAP: statically allocate >80 KB LDS so at most ONE 512-thread
// workgroup (8 waves = 2 waves/EU) fits per CU. The backend's achievable-
// occupancy estimate (getOccupancyWithLocalMemSize) then bounds occupancy at
// 2 waves/EU, giving the register allocator a 256-VGPR budget with zero
// occupancy cost -> the 128 weight floats stay RESIDENT and MachineLICM can
// hoist the weight loads out of the 20000-iteration loop (R2-R4: VGPR=80-88,
// loads stayed in the loop, ~256 KB/step re-read through L1/L2).
__global__ __launch_bounds__(512)
__attribute__((amdgpu_waves_per_eu(2, 2)))
void k_lstm(const float* __restrict__ g_in, const float* __restrict__ wp,
            float* __restrict__ hs, int T) {
  const int t = threadIdx.x;
  const int q = t >> 2;        // unit 0..127
  const int pos = t & 3;       // gate slot: 0=i 1=f 2=g 3=o
  const int row = pos * 128 + q;

  __shared__ __align__(16) float hbuf[2][144];   // skew: h[q] at q + 4*(q>>5)
  __shared__ float lds_cap[20736];               // 82944 B occupancy anchor

  // touch the anchor so it is not eliminated (one store, outside the loop)
  if (t == 0) {
    volatile float* vp = lds_cap;
    vp[0] = 0.f;
  }

  // 128 weight floats in VGPRs as 64 packed pairs
  v2f wq[64];
  {
    const float4* wr = (const float4*)(wp + (size_t)t * 128);
#pragma unroll
    for (int k = 0; k < 32; ++k) {
      float4 wv = wr[k];
      wq[2 * k + 0] = (v2f){wv.x, wv.y};
      wq[2 * k + 1] = (v2f){wv.z, wv.w};
    }
  }
  if (t < 144) { hbuf[0][t] = 0.f; hbuf[1][t] = 0.f; }
  float c = 0.f;
  float gn = g_in[row];
  __syncthreads();

  int pb = 0;
  const bool isg = (pos == 2);
  const bool sw1 = (pos & 1);
  const bool sw2 = (pos & 2) != 0;

  for (int step = 0; step < T; ++step) {
    float gcur = gn;
    size_t nb = (size_t)(step + 1 < T ? step + 1 : step) * G4;
    gn = g_in[nb + row];               // prefetch next step's input

    const float4* hb = (const float4*)&hbuf[pb][36 * pos];
    v2f a0 = {0.f, 0.f}, a1 = {0.f, 0.f}, a2 = {0.f, 0.f}, a3 = {0.f, 0.f};
#pragma unroll
    for (int jj = 0; jj < 8; ++jj) {
      float4 hv = hb[jj];
      v2f hlo = (v2f){hv.x, hv.y};
      v2f hhi = (v2f){hv.z, hv.w};
      a0 = __builtin_elementwise_fma(wq[0 * 16 + 2 * jj], hlo, a0);
      a0 = __builtin_elementwise_fma(wq[0 * 16 + 2 * jj + 1], hhi, a0);
      a1 = __builtin_elementwise_fma(wq[1 * 16 + 2 * jj], hlo, a1);
      a1 = __builtin_elementwise_fma(wq[1 * 16 + 2 * jj + 1], hhi, a1);
      a2 = __builtin_elementwise_fma(wq[2 * 16 + 2 * jj], hlo, a2);
      a2 = __builtin_elementwise_fma(wq[2 * 16 + 2 * jj + 1], hhi, a2);
      a3 = __builtin_elementwise_fma(wq[3 * 16 + 2 * jj], hlo, a3);
      a3 = __builtin_elementwise_fma(wq[3 * 16 + 2 * jj + 1], hhi, a3);
    }
    float s0 = a0.x + a0.y;
    float s1 = a1.x + a1.y;
    float s2 = a2.x + a2.y;
    float s3 = a3.x + a3.y;

    // quad butterfly-REDUCE: lane p ends with gate p's full preactivation
    float send_lo = sw1 ? s0 : s1;
    float send_hi = sw1 ? s2 : s3;
    float keep_lo = sw1 ? s1 : s0;
    float keep_hi = sw1 ? s3 : s2;
    float r_lo = keep_lo + dpp_xor1(send_lo);   // gate (p&1)
    float r_hi = keep_hi + dpp_xor1(send_hi);   // gate (p&1)+2
    float send2 = sw2 ? r_lo : r_hi;
    float keep2 = sw2 ? r_hi : r_lo;
    float x = keep2 + dpp_xor2(send2) + gcur;   // gate p total

    // activation: pos==2 -> tanh (as 2*sig(2x)-1), else sigmoid
    float xs = isg ? 2.f * x : x;
    float e = __expf(-xs);
    float r = frcp(1.f + e);
    float a = isg ? 2.f * r - 1.f : r;

    // quad butterfly-GATHER: every lane collects all 4 gate activations
    float b = dpp_xor1(a);
    float c2 = dpp_xor2(a);
    float d2 = dpp_xor2(b);
    float p0 = sw1 ? b : a;
    float p1 = sw1 ? a : b;
    float p2 = sw1 ? d2 : c2;
    float p3 = sw1 ? c2 : d2;
    float i_ = sw2 ? p2 : p0;
    float f_ = sw2 ? p3 : p1;
    float g_ = sw2 ? p0 : p2;
    float o_ = sw2 ? p1 : p3;

    c = __builtin_fmaf(f_, c, i_ * g_);   // all 4 lanes redundantly
    float h = o_ * ftanh(c);

    pb ^= 1;
    if (pos == 0) {
      hbuf[pb][q + ((q >> 5) << 2)] = h;
      hs[(size_t)step * NF + q] = h;
    }
    __syncthreads();
  }
}

// ---------------- host launch ----------------

extern "C" void kernel_launch(void* const* d_in, const int* in_sizes, int n_in,
                              void* d_out, int out_size, void* d_ws, size_t ws_size,
                              hipStream_t stream) {
  const float* x     = (const float*)d_in[0];
  const void* edges  = d_in[1];
  const float* W1    = (const float*)d_in[2];
  const float* b1    = (const float*)d_in[3];
  const float* W2    = (const float*)d_in[4];
  const float* b2    = (const float*)d_in[5];
  const float* W_ih  = (const float*)d_in[6];
  const float* W_hh  = (const float*)d_in[7];
  const float* b_ih  = (const float*)d_in[8];
  const float* b_hh  = (const float*)d_in[9];
  const float* W_lin = (const float*)d_in[10];
  const float* b_lin = (const float*)d_in[11];
  float* out = (float*)d_out;

  const int N = in_sizes[0] / NF;  // 20000
  const int E = in_sizes[1] / 2;   // 640000
  const int OUTF = 64;

  char* base = (char*)d_ws;
  size_t off = 0;
  auto alloc = [&](size_t b) {
    char* p = base + off;
    off += (b + 255) & ~(size_t)255;
    return p;
  };
  float* dinv = (float*)alloc((size_t)N * 4);
  float* W1T  = (float*)alloc(128 * 128 * 4);
  float* W2T  = (float*)alloc(128 * 128 * 4);
  float* wp   = (float*)alloc(512 * 128 * 4);
  float* bsum = (float*)alloc(512 * 4);
  int*   flag = (int*)alloc(256);
  float* bufA = (float*)alloc((size_t)N * NF * 4);
  float* bufB = (float*)alloc((size_t)N * NF * 4);
  float* bufC = (float*)alloc((size_t)N * NF * 4);
  float* g_in = (float*)alloc((size_t)N * (size_t)G4 * 4);
  if (off > ws_size) return;

  k_fill<<<(N + 255) / 256, 256, 0, stream>>>(dinv, 1.0f, N);
  k_detect_i64<<<1, 1, 0, stream>>>((const int*)edges, 1024, flag);
  k_count<<<(E + 255) / 256, 256, 0, stream>>>(edges, flag, dinv, E);
  k_rsqrt<<<(N + 255) / 256, 256, 0, stream>>>(dinv, N);
  k_t128<<<128, 128, 0, stream>>>(W1, W1T);
  k_t128<<<128, 128, 0, stream>>>(W2, W2T);
  k_wprep<<<512, 128, 0, stream>>>(W_hh, wp);
  k_add<<<2, 256, 0, stream>>>(b_ih, b_hh, bsum, 512);

  const int mg = (N + 63) / 64;

  gemm_bt<<<dim3(mg, 2), 256, 0, stream>>>(x, W1T, nullptr, bufA, N, NF, NF);
  hipMemsetAsync(bufB, 0, (size_t)N * NF * 4, stream);
  k_aggregate<<<(E + 7) / 8, 256, 0, stream>>>(bufA, edges, flag, dinv, bufB, E);
  k_finish<<<(N * 32 + 255) / 256, 256, 0, stream>>>(bufB, bufA, dinv, b1, N);

  gemm_bt<<<dim3(mg, 2), 256, 0, stream>>>(bufB, W2T, nullptr, bufA, N, NF, NF);
  hipMemsetAsync(bufC, 0, (size_t)N * NF * 4, stream);
  k_aggregate<<<(E + 7) / 8, 256, 0, stream>>>(bufA, edges, flag, dinv, bufC, E);
  k_finish<<<(N * 32 + 255) / 256, 256, 0, stream>>>(bufC, bufA, dinv, b2, N);

  gemm_bt<<<dim3(mg, 8), 256, 0, stream>>>(bufC, W_ih, bsum, g_in, N, G4, NF);

  k_lstm<<<1, 512, 0, stream>>>(g_in, wp, bufB, N);

  gemm_bt<<<dim3(mg, 1), 256, 0, stream>>>(bufB, W_lin, b_lin, out, N, OUTF, NF);
}